// Round 9
// baseline (466.755 us; speedup 1.0000x reference)
//
#include <hip/hip_runtime.h>
#include <string.h>

// TopographicIntentMap R9: R7 base (362us, single AoS stream, mov-free depth-2
// pipeline) + two surgical VALU cuts. R8's split-stream regressed (halved
// prefetch distance -> latency-exposed); reverted.
//  (1) dual f64 accumulators per 4-entry block: halves the serial FMA chain.
//      Exact: all partial sums are exact in f64 (products <=29 bits, spread
//      <=23 bits); order-insensitivity already proven empirically (R4/R5).
//  (2) tick loop unrolled x2 with compile-time double-buffer offsets: the
//      ds_read immediate absorbs the buffer base -> 1 v_add per gather.
// Numerics: identical exact-f64 pipeline as R3-R8 (absmax 0 every round).

#define NN 144
#define NE 115
#define NB 64            // batches per block (= lanes)
#define RPW 9            // rows per wave: 16*9 = 144
#define THREADS 1024

// ws layout: int rowptr[145] at 0; padded (x4) CSR entries at byte 4096,
// 8B each: {u32 colByte=col*256, f32 w}; 16-entry zero tail.
#define CSR_BYTE_OFF 4096

__device__ __forceinline__ float u2f(unsigned u) {
    float f; memcpy(&f, &u, 4); return f;
}

__global__ void prep_kernel(const float* __restrict__ W_rec,
                            int* __restrict__ wsI, char* __restrict__ wsB) {
    __shared__ int cnt[NN];
    __shared__ int rp[NN + 1];
    int t = threadIdx.x;

    if (t < NN) {
        int c = 0;
        for (int j = 0; j < NN; ++j) c += (W_rec[t * NN + j] != 0.0f);
        cnt[t] = c;
    }
    __syncthreads();
    if (t == 0) {
        int s = 0; rp[0] = 0;
        for (int o = 0; o < NN; ++o) { s += (cnt[o] + 3) & ~3; rp[o + 1] = s; }
    }
    __syncthreads();
    if (t <= NN) wsI[t] = rp[t];
    char* base = wsB + CSR_BYTE_OFF;
    if (t < NN) {
        int p = rp[t];
        for (int j = 0; j < NN; ++j) {
            float w = W_rec[t * NN + j];
            if (w != 0.0f) {
                *(unsigned*)(base + 8 * (size_t)p) = (unsigned)j * 256u;
                *(float*)(base + 8 * (size_t)p + 4) = w;
                ++p;
            }
        }
        for (; p < rp[t + 1]; ++p) {                 // zero-weight pads (exact)
            *(unsigned*)(base + 8 * (size_t)p)  = 0u;
            *(float*)(base + 8 * (size_t)p + 4) = 0.0f;
        }
    }
    if (t < 16) {                                    // pipeline-overrun tail
        int p = rp[NN] + t;
        *(unsigned*)(base + 8 * (size_t)p)  = 0u;
        *(float*)(base + 8 * (size_t)p + 4) = 0.0f;
    }
}

// 4 entries from two uint4 regs; dual accumulators rec0/rec1 (exact f64).
// RBUF is a compile-time float* (accF[0] or accF[1]) so the buffer offset
// folds into the ds_read immediate.
#define GFMA4(RBUF, S0, S1)                                             \
    {                                                                   \
        float a0 = *(const float*)((const char*)(RBUF) + ((S0).x + laneB)); \
        float a1 = *(const float*)((const char*)(RBUF) + ((S0).z + laneB)); \
        float a2 = *(const float*)((const char*)(RBUF) + ((S1).x + laneB)); \
        float a3 = *(const float*)((const char*)(RBUF) + ((S1).z + laneB)); \
        rec0 += (double)u2f((S0).y) * (double)a0;                       \
        rec0 += (double)u2f((S0).w) * (double)a1;                       \
        rec1 += (double)u2f((S1).y) * (double)a2;                       \
        rec1 += (double)u2f((S1).w) * (double)a3;                       \
    }

// one tick: read RBUF (compile-time), write WBUF (compile-time)
#define TICK_BODY(RBUF, WBUF)                                           \
    {                                                                   \
        __syncthreads();                                                \
        const uint4* p = pBase;                                         \
        uint4 SA0 = p[0], SA1 = p[1];                                   \
        uint4 SB0 = p[2], SB1 = p[3];                                   \
        _Pragma("unroll")                                               \
        for (int r = 0; r < RPW; ++r) {                                 \
            const int o = R0 + r;                                       \
            double rec0 = 0.0, rec1 = 0.0;                              \
            int k = sk0[r];                                             \
            const int kend = sk1[r];                                    \
            while (k + 8 <= kend) {                                     \
                GFMA4(RBUF, SA0, SA1);                                  \
                SA0 = p[4]; SA1 = p[5];                                 \
                GFMA4(RBUF, SB0, SB1);                                  \
                SB0 = p[6]; SB1 = p[7];                                 \
                p += 4; k += 8;                                         \
            }                                                           \
            if (k < kend) {                                             \
                GFMA4(RBUF, SA0, SA1);                                  \
                SA0 = SB0; SA1 = SB1;                                   \
                SB0 = p[4]; SB1 = p[5];                                 \
                p += 2;                                                 \
            }                                                           \
            double rec = rec0 + rec1;  /* exact: sum fits 52 bits */    \
            double x = drv[r] + 0.3 * ((o < NE) ? rec : -rec);          \
            double vv = v[r];                                           \
            vv += (x - vv) * 0.5;                                       \
            double s = (vv >= 1.0) ? 1.0 : 0.0;                         \
            vv *= (1.0 - s);                                            \
            v[r] = vv;                                                  \
            accv[r] += (float)s;                                        \
            (WBUF)[(o << 6) + lane] = accv[r];                          \
        }                                                               \
    }

__global__ __launch_bounds__(THREADS) void snn_kernel(
        const int*   __restrict__ actions,
        const float* __restrict__ spk,      // [B,8,115]
        const float* __restrict__ W_inh,    // [144,115]
        const int*   __restrict__ wsI,      // padded rowptr
        const uint4* __restrict__ csrQ,     // 2 entries per uint4
        const int*   __restrict__ nt_ptr,
        float*       __restrict__ out,      // [B,115]
        int B) {
    __shared__ float accF0[NN * NB];        // double buffer, split for
    __shared__ float accF1[NN * NB];        // compile-time addressing
    __shared__ int   rpL[NN + 1];

    float* nbF = accF1;                     // [NE][65] alias, pre-loop only

    const int t    = threadIdx.x;
    const int lane = t & 63;
    const int wid  = t >> 6;
    const int b0   = blockIdx.x * NB;
    const int b    = b0 + lane;
    const int ticks = *nt_ptr;
    const int R0   = wid * RPW;
    const unsigned laneB = (unsigned)lane * 4u;

    // opaque per-lane zero: keeps the CSR stream on the vector VMEM path
    int vz;
    asm volatile("v_mov_b32 %0, 0" : "=v"(vz));

    if (t <= NN) rpL[t] = wsI[t];

    // stage neighbor sums into nbF[e][bb]
    for (int p = t; p < NB * NE; p += THREADS) {
        int bb = p / NE;
        int e  = p - bb * NE;
        float s = 0.0f;
        if (b0 + bb < B) {
            const float* sp = spk + ((size_t)(b0 + bb) * 8) * NE + e;
            #pragma unroll
            for (int n = 0; n < 8; ++n) s += sp[n * NE];
        }
        nbF[e * (NB + 1) + bb] = s;
    }
    for (int i = t; i < NN * NB; i += THREADS) accF0[i] = 0.0f;
    __syncthreads();

    // per-row drives (fp64, e ascending — unchanged association)
    const int R0s = __builtin_amdgcn_readfirstlane(R0);
    double drv[RPW];
    {
        int a = (b < B) ? actions[b] : 4;
        int cell = (a == 0) ? 5 : (a == 1) ? 1 : (a == 2) ? 3 : (a == 3) ? 7 : 4;
        int cs = cell * 16;
        #pragma unroll
        for (int r = 0; r < RPW; ++r) {
            double inh = 0.0;
            for (int e = 0; e < NE; ++e)
                inh += (double)nbF[e * (NB + 1) + lane]
                     * (double)W_inh[(R0s + r) * NE + e];
            int o = R0 + r;
            double ic = (o >= cs && o < cs + 16) ? 5.0 : 0.0;
            drv[r] = 0.5 * ic - 0.5 * inh;
        }
    }

    int sk0[RPW], sk1[RPW];
    #pragma unroll
    for (int r = 0; r < RPW; ++r) {
        sk0[r] = __builtin_amdgcn_readfirstlane(rpL[R0 + r]);
        sk1[r] = __builtin_amdgcn_readfirstlane(rpL[R0 + r + 1]);
    }
    const uint4* pBase = csrQ + (sk0[0] >> 1) + vz;   // per-lane ptr (VMEM)

    double v[RPW];
    float  accv[RPW];
    #pragma unroll
    for (int r = 0; r < RPW; ++r) { v[r] = 0.0; accv[r] = 0.0f; }

    // ticks is even (30) in practice; handle odd counts with a final tick.
    int tk = 0;
    for (; tk + 2 <= ticks; tk += 2) {
        TICK_BODY(accF0, accF1);
        TICK_BODY(accF1, accF0);
    }
    if (tk < ticks) TICK_BODY(accF0, accF1);

    if (b < B) {
        #pragma unroll
        for (int r = 0; r < RPW; ++r) {
            int o = R0 + r;
            if (o < NE) out[(size_t)b * NE + o] = accv[r];
        }
    }
}

extern "C" void kernel_launch(void* const* d_in, const int* in_sizes, int n_in,
                              void* d_out, int out_size, void* d_ws, size_t ws_size,
                              hipStream_t stream) {
    const int*   actions = (const int*)  d_in[0];
    const float* spk     = (const float*)d_in[1];
    const float* W_rec   = (const float*)d_in[2];
    const float* W_inh   = (const float*)d_in[3];
    const int*   nt      = (const int*)  d_in[4];
    float* out = (float*)d_out;
    int B = in_sizes[0];

    int*  wsI = (int*)d_ws;
    char* wsB = (char*)d_ws;
    const uint4* csrQ = (const uint4*)(wsB + CSR_BYTE_OFF);

    prep_kernel<<<1, 256, 0, stream>>>(W_rec, wsI, wsB);
    int nblocks = (B + NB - 1) / NB;
    snn_kernel<<<nblocks, THREADS, 0, stream>>>(actions, spk, W_inh, wsI, csrQ,
                                                nt, out, B);
}

// Round 10
// 383.476 us; speedup vs baseline: 1.2172x; 1.2172x over previous
//
#include <hip/hip_runtime.h>
#include <string.h>

// TopographicIntentMap R10: R7 skeleton + both per-entry cvts removed.
// R8 lesson: don't split the stream (latency). R9 lesson: don't duplicate the
// tick body (scratch spills, WRITE_SIZE 329MB). This round keeps ONE tick
// body and ONE 8B/entry stream:
//   entry u64 = double_as_u64((double)w) | (col*512)   [(double)w has 29 zero
//   low mantissa bits; col*512 needs 17 -> exact recovery via and/xor]
//   acc in LDS as f64 (integers <= 30, exact), double-buffered, 1 barrier/tick.
// Per-entry: v_and + v_xor + v_add + ds_read_b64 + v_fma_f64 (~10-12cy VALU).
// DS pipe becomes the cap: 2506x30x5.8 = 436K cyc = 182us floor.
// Numerics: BIT-IDENTICAL f64 pipeline to R3-R9 (absmax 0 every round).

#define NN 144
#define NE 115
#define NB 64            // batches per block (= lanes)
#define RPW 9            // rows per wave: 16*9 = 144
#define THREADS 1024

// ws layout: int rowptr[145] at 0; padded (x4) packed entries at byte 4096,
// 8B each; 16-entry zero tail.
#define CSR_BYTE_OFF 4096

__device__ __forceinline__ double u2d(unsigned lo, unsigned hi) {
    unsigned long long u = ((unsigned long long)hi << 32) | lo;
    double d; memcpy(&d, &u, 8); return d;
}

__global__ void prep_kernel(const float* __restrict__ W_rec,
                            int* __restrict__ wsI, char* __restrict__ wsB) {
    __shared__ int cnt[NN];
    __shared__ int rp[NN + 1];
    int t = threadIdx.x;

    if (t < NN) {
        int c = 0;
        for (int j = 0; j < NN; ++j) c += (W_rec[t * NN + j] != 0.0f);
        cnt[t] = c;
    }
    __syncthreads();
    if (t == 0) {
        int s = 0; rp[0] = 0;
        for (int o = 0; o < NN; ++o) { s += (cnt[o] + 3) & ~3; rp[o + 1] = s; }
    }
    __syncthreads();
    if (t <= NN) wsI[t] = rp[t];
    unsigned long long* ent = (unsigned long long*)(wsB + CSR_BYTE_OFF);
    if (t < NN) {
        int p = rp[t];
        for (int j = 0; j < NN; ++j) {
            float w = W_rec[t * NN + j];
            if (w != 0.0f) {
                double dw = (double)w;
                unsigned long long ub; memcpy(&ub, &dw, 8);
                ub |= (unsigned long long)((unsigned)j * 512u);  // 17 low bits
                ent[p] = ub;
                ++p;
            }
        }
        for (; p < rp[t + 1]; ++p) ent[p] = 0ull;   // zero pads: exact no-ops
    }
    if (t < 16) ent[rp[NN] + t] = 0ull;             // pipeline-overrun tail
}

// 2 packed entries from one uint4 S = {lo0,hi0,lo1,hi1}; exact f64 FMAs.
#define GFMA2(S)                                                        \
    {                                                                   \
        unsigned c0 = (S).x & 0x1FFFFu;                                 \
        unsigned l0 = (S).x ^ c0;                                       \
        unsigned c1 = (S).z & 0x1FFFFu;                                 \
        unsigned l1 = (S).z ^ c1;                                       \
        double a0 = *(const double*)(ldsB + (c0 + lro));                \
        double a1 = *(const double*)(ldsB + (c1 + lro));                \
        rec += u2d(l0, (S).y) * a0;                                     \
        rec += u2d(l1, (S).w) * a1;                                     \
    }

__global__ __launch_bounds__(THREADS) void snn_kernel(
        const int*   __restrict__ actions,
        const float* __restrict__ spk,      // [B,8,115]
        const float* __restrict__ W_inh,    // [144,115]
        const int*   __restrict__ wsI,      // padded rowptr
        const uint4* __restrict__ csrQ,     // 2 packed entries per uint4
        const int*   __restrict__ nt_ptr,
        float*       __restrict__ out,      // [B,115]
        int B) {
    __shared__ double accD[2 * NN * NB];    // 147456 B, double-buffered
    __shared__ int    rpL[NN + 1];

    float* nbF = (float*)&accD[NN * NB];    // [NE][65] alias, pre-loop only
    const char* ldsB = (const char*)accD;   // gather base (compile-time LDS)

    const int t    = threadIdx.x;
    const int lane = t & 63;
    const int wid  = t >> 6;
    const int b0   = blockIdx.x * NB;
    const int b    = b0 + lane;
    const int ticks = *nt_ptr;
    const int R0   = wid * RPW;
    const unsigned laneB8 = (unsigned)lane * 8u;

    // opaque per-lane zero: keeps the packed stream on the vector VMEM path
    int vz;
    asm volatile("v_mov_b32 %0, 0" : "=v"(vz));

    if (t <= NN) rpL[t] = wsI[t];

    // stage neighbor sums into nbF[e][bb]
    for (int p = t; p < NB * NE; p += THREADS) {
        int bb = p / NE;
        int e  = p - bb * NE;
        float s = 0.0f;
        if (b0 + bb < B) {
            const float* sp = spk + ((size_t)(b0 + bb) * 8) * NE + e;
            #pragma unroll
            for (int n = 0; n < 8; ++n) s += sp[n * NE];
        }
        nbF[e * (NB + 1) + bb] = s;
    }
    for (int i = t; i < NN * NB; i += THREADS) accD[i] = 0.0;
    __syncthreads();

    // per-row drives (fp64, e ascending — unchanged association)
    const int R0s = __builtin_amdgcn_readfirstlane(R0);
    double drv[RPW];
    {
        int a = (b < B) ? actions[b] : 4;
        int cell = (a == 0) ? 5 : (a == 1) ? 1 : (a == 2) ? 3 : (a == 3) ? 7 : 4;
        int cs = cell * 16;
        #pragma unroll
        for (int r = 0; r < RPW; ++r) {
            double inh = 0.0;
            for (int e = 0; e < NE; ++e)
                inh += (double)nbF[e * (NB + 1) + lane]
                     * (double)W_inh[(R0s + r) * NE + e];
            int o = R0 + r;
            double ic = (o >= cs && o < cs + 16) ? 5.0 : 0.0;
            drv[r] = 0.5 * ic - 0.5 * inh;
        }
    }

    int sk0[RPW], sk1[RPW];
    #pragma unroll
    for (int r = 0; r < RPW; ++r) {
        sk0[r] = __builtin_amdgcn_readfirstlane(rpL[R0 + r]);
        sk1[r] = __builtin_amdgcn_readfirstlane(rpL[R0 + r + 1]);
    }
    const uint4* pBase = csrQ + (sk0[0] >> 1) + vz;   // per-lane ptr (VMEM)

    double v[RPW];
    float  accv[RPW];
    #pragma unroll
    for (int r = 0; r < RPW; ++r) { v[r] = 0.0; accv[r] = 0.0f; }

    for (int tk = 0; tk < ticks; ++tk) {
        __syncthreads();   // prev tick's acc writes (or initial zeros) visible
        const unsigned rbOff = (tk & 1) ? (unsigned)(NN * NB * 8) : 0u;
        const unsigned lro   = laneB8 + rbOff;          // folded gather offset
        double* __restrict__ Wb = accD + ((tk & 1) ? 0 : NN * NB);

        // prime: SA = entries k..k+3 (2 uint4), SB = k+4..k+7 (flat stream)
        const uint4* p = pBase;
        uint4 SA0 = p[0], SA1 = p[1];
        uint4 SB0 = p[2], SB1 = p[3];

        #pragma unroll
        for (int r = 0; r < RPW; ++r) {
            const int o = R0 + r;
            double rec = 0.0;
            int k = sk0[r];
            const int kend = sk1[r];
            // steady state: 2 chunks (8 entries)/iter, zero rotation movs
            while (k + 8 <= kend) {
                GFMA2(SA0); GFMA2(SA1);
                SA0 = p[4]; SA1 = p[5];          // entries k+8..k+11
                GFMA2(SB0); GFMA2(SB1);
                SB0 = p[6]; SB1 = p[7];          // entries k+12..k+15
                p += 4; k += 8;
            }
            if (k < kend) {                      // one leftover 4-entry chunk
                GFMA2(SA0); GFMA2(SA1);
                SA0 = SB0; SA1 = SB1;            // once-per-odd-row movs
                SB0 = p[4]; SB1 = p[5];
                p += 2;
            }
            // invariant: SA = next row's first chunk, SB = second
            double x = drv[r] + 0.3 * ((o < NE) ? rec : -rec);
            double vv = v[r];
            vv += (x - vv) * 0.5;
            double s = (vv >= 1.0) ? 1.0 : 0.0;
            vv *= (1.0 - s);
            v[r] = vv;
            accv[r] += (float)s;
            Wb[(o << 6) + lane] = (double)accv[r];   // exact integer
        }
    }

    if (b < B) {
        #pragma unroll
        for (int r = 0; r < RPW; ++r) {
            int o = R0 + r;
            if (o < NE) out[(size_t)b * NE + o] = accv[r];
        }
    }
}

extern "C" void kernel_launch(void* const* d_in, const int* in_sizes, int n_in,
                              void* d_out, int out_size, void* d_ws, size_t ws_size,
                              hipStream_t stream) {
    const int*   actions = (const int*)  d_in[0];
    const float* spk     = (const float*)d_in[1];
    const float* W_rec   = (const float*)d_in[2];
    const float* W_inh   = (const float*)d_in[3];
    const int*   nt      = (const int*)  d_in[4];
    float* out = (float*)d_out;
    int B = in_sizes[0];

    int*  wsI = (int*)d_ws;
    char* wsB = (char*)d_ws;
    const uint4* csrQ = (const uint4*)(wsB + CSR_BYTE_OFF);

    prep_kernel<<<1, 256, 0, stream>>>(W_rec, wsI, wsB);
    int nblocks = (B + NB - 1) / NB;
    snn_kernel<<<nblocks, THREADS, 0, stream>>>(actions, spk, W_inh, wsI, csrQ,
                                                nt, out, B);
}